// Round 3
// baseline (1837.582 us; speedup 1.0000x reference)
//
#include <hip/hip_runtime.h>
#include <hip/hip_bf16.h>

// MyRnn: h_t = tanh(emb[idx_t] @ W_xh + b_h + h_{t-1} @ W_hh), 80 steps,
// out = sigmoid(h_80 @ W_out + b_out).
//
// R3: kill the spills (R1/R2 post-mortem: WRITE=36MB spill stores + FETCH=1GB
// reloads). 64 blocks x 256 thr (4 waves, 1 wave/SIMD, launch_bounds(256,1)
// -> 512 unified regs/wave). M=32 batch rows/block, each wave owns 128 cols
// (NT=8). Resident in regs: W_xh (4 ksteps, 128 regs) + W_hh ksteps 0..3
// (128 regs). W_hh ksteps 4..15 streamed from L2 every step (384 KB/CU/step
// ~ 4.7 TB/s/XCD ~ L2 ceiling), 3-deep software pipeline (h-independent
// loads -> issued ~234cyc + resident-MFMA head start before use).
// h double-buffers through XOR-swizzled LDS; ONE __syncthreads per step.
// 4 waves (not 8) halves redundant LDS A-frag traffic (all waves read the
// same h rows).

#define T_LEN   80
#define EMB_D   100
#define UNITS   512
#define ROWS    32
#define NBLK    64               // 2048/32
#define NTHR    256
#define NW      4
#define NT      8                // 16-col n-tiles per wave (128 cols)
#define KSH     16               // hh K-steps (512/32)
#define KSX     4                // x K-steps (128/32, zero-padded)
#define RKS     4                // resident hh ksteps
#define SDEPTH  3                // streamed pipeline depth

typedef __bf16 bf16x8 __attribute__((ext_vector_type(8)));
typedef float  f32x4  __attribute__((ext_vector_type(4)));

__device__ __forceinline__ float fast_tanh(float x) {
    float e = __builtin_amdgcn_exp2f(x * 2.8853900817779268f);
    return 1.0f - 2.0f * __builtin_amdgcn_rcpf(1.0f + e);
}

// ---- prep: transpose + bf16-cast weights into d_ws ----
__global__ void prep_kernel(const float* __restrict__ Whh,
                            const float* __restrict__ Wxh,
                            __bf16* __restrict__ Wt, __bf16* __restrict__ Xt) {
    __shared__ float tile[32][33];
    const int tx = threadIdx.x & 31, ty = threadIdx.x >> 5;  // 32x8
    const int b = blockIdx.x;
    if (b < 256) {
        const int k0 = (b & 15) * 32, n0 = (b >> 4) * 32;
        #pragma unroll
        for (int i = 0; i < 4; ++i)
            tile[ty + 8 * i][tx] = Whh[(k0 + ty + 8 * i) * UNITS + n0 + tx];
        __syncthreads();
        #pragma unroll
        for (int i = 0; i < 4; ++i) {
            const int n = ty + 8 * i;
            Wt[(n0 + n) * UNITS + k0 + tx] = (__bf16)tile[tx][n];
        }
    } else {
        const int bb = b - 256;
        const int k0 = (bb & 3) * 32, n0 = (bb >> 2) * 32;
        #pragma unroll
        for (int i = 0; i < 4; ++i) {
            const int k = k0 + ty + 8 * i;
            tile[ty + 8 * i][tx] = (k < EMB_D) ? Wxh[k * UNITS + n0 + tx] : 0.0f;
        }
        __syncthreads();
        #pragma unroll
        for (int i = 0; i < 4; ++i) {
            const int n = ty + 8 * i;
            Xt[(n0 + n) * 128 + k0 + tx] = (__bf16)tile[tx][n];
        }
    }
}

__global__ __launch_bounds__(NTHR, 1)
void rnn_kernel(const int*   __restrict__ inputs,   // [2048][80]
                const float* __restrict__ emb,      // [35000][100]
                const float* __restrict__ bh,       // [512]
                const float* __restrict__ Wout,     // [512]
                const float* __restrict__ bout,     // [1]
                const __bf16* __restrict__ Wt,      // [512 n][512 k] (ws)
                const __bf16* __restrict__ Xt,      // [512 n][128 k] (ws)
                float*       __restrict__ out)      // [2048]
{
    // h: 32 rows x 512 bf16; elem(r,k) = r*512 + (((k>>3)^(r&7))<<3) + (k&7)
    // x: 32 rows x 128 bf16; same swizzle, row stride 128.
    __shared__ alignas(16) __bf16 hbuf[2][ROWS * UNITS];  // 2 x 32 KB
    __shared__ alignas(16) __bf16 xbuf[2][ROWS * 128];    // 2 x 8 KB

    const int tid  = threadIdx.x;
    const int wave = tid >> 6;       // 0..3
    const int lane = tid & 63;
    const int q    = lane >> 4;
    const int ln   = lane & 15;
    const int e7   = ln & 7;
    const int qa   = q ^ (e7 & 3);
    const int kx   = e7 >> 2;
    const int q8   = q << 3;
    const int r0   = blockIdx.x * ROWS;

    // per-nt element offsets into Wt (base + woff + ks*32 -> one 16B load)
    int   woff[NT];
    float bhv[NT];
    #pragma unroll
    for (int nt = 0; nt < NT; ++nt) {
        const int col = (wave << 7) + (nt << 4) + ln;
        woff[nt] = col * UNITS + q8;
        bhv[nt]  = bh[col];
    }

    // resident fragments (AGPR-eligible: only ever MFMA B operands)
    bf16x8 whh[RKS][NT];
    bf16x8 wxh[KSX][NT];
    #pragma unroll
    for (int nt = 0; nt < NT; ++nt) {
        const int xo = ((wave << 7) + (nt << 4) + ln) * 128 + q8;
        #pragma unroll
        for (int ks = 0; ks < RKS; ++ks)
            whh[ks][nt] = *(const bf16x8*)(Wt + woff[nt] + (ks << 5));
        #pragma unroll
        for (int ks = 0; ks < KSX; ++ks)
            wxh[ks][nt] = *(const bf16x8*)(Xt + xo + (ks << 5));
    }

    // zero LDS: hbuf[0] (h0 = 0) and both xbuf (pad cols k>=100 stay 0)
    {
        int4 z; z.x = z.y = z.z = z.w = 0;
        int4* hp = (int4*)&hbuf[0][0];
        #pragma unroll
        for (int i = 0; i < 8; ++i) hp[tid + i * NTHR] = z;   // 32 KB
        int4* xp = (int4*)&xbuf[0][0];
        #pragma unroll
        for (int i = 0; i < 4; ++i) xp[tid + i * NTHR] = z;   // 16 KB
    }
    __syncthreads();

    // stage embedded x_t (bf16, swizzled); wave handles 8 rows
    auto stage = [&](int t, __bf16* xb) {
        #pragma unroll
        for (int rr = 0; rr < 8; ++rr) {
            const int r = (wave << 3) + rr;
            const int idxv = inputs[(r0 + r) * T_LEN + t];
            const float* er = emb + (size_t)idxv * EMB_D;
            const int k0 = lane;          // < 100 always
            xb[(r << 7) + ((((k0 >> 3) ^ (r & 7)) << 3) | (k0 & 7))] = (__bf16)er[k0];
            const int k1 = lane + 64;
            if (k1 < EMB_D)
                xb[(r << 7) + ((((k1 >> 3) ^ (r & 7)) << 3) | (k1 & 7))] = (__bf16)er[k1];
        }
    };

    auto step = [&](const __bf16* hb_r, const __bf16* xb_r, __bf16* hb_w) {
        // prefetch first SDEPTH streamed ksteps (no dependence on h/barrier)
        bf16x8 sB[SDEPTH][NT];
        #pragma unroll
        for (int p = 0; p < SDEPTH; ++p)
            #pragma unroll
            for (int nt = 0; nt < NT; ++nt)
                sB[p][nt] = *(const bf16x8*)(Wt + woff[nt] + ((RKS + p) << 5));

        f32x4 acc[2][NT];
        #pragma unroll
        for (int mt = 0; mt < 2; ++mt)
            #pragma unroll
            for (int nt = 0; nt < NT; ++nt) {
                f32x4 a = {bhv[nt], bhv[nt], bhv[nt], bhv[nt]};
                acc[mt][nt] = a;
            }

        // x contribution (resident wxh) — gives streamed loads a head start
        const int xb0 = (ln << 7) + (qa << 3);
        #pragma unroll
        for (int ks = 0; ks < KSX; ++ks) {
            const bf16x8 a0 = *(const bf16x8*)&xb_r[xb0 + ((ks ^ kx) << 5)];
            const bf16x8 a1 = *(const bf16x8*)&xb_r[xb0 + (16 << 7) + ((ks ^ kx) << 5)];
            #pragma unroll
            for (int nt = 0; nt < NT; ++nt)
                acc[0][nt] = __builtin_amdgcn_mfma_f32_16x16x32_bf16(a0, wxh[ks][nt], acc[0][nt], 0, 0, 0);
            #pragma unroll
            for (int nt = 0; nt < NT; ++nt)
                acc[1][nt] = __builtin_amdgcn_mfma_f32_16x16x32_bf16(a1, wxh[ks][nt], acc[1][nt], 0, 0, 0);
        }
        // resident hh ksteps
        const int hb0 = (ln << 9) + (qa << 3);
        #pragma unroll
        for (int ks = 0; ks < RKS; ++ks) {
            const bf16x8 a0 = *(const bf16x8*)&hb_r[hb0 + ((ks ^ kx) << 5)];
            const bf16x8 a1 = *(const bf16x8*)&hb_r[hb0 + (16 << 9) + ((ks ^ kx) << 5)];
            #pragma unroll
            for (int nt = 0; nt < NT; ++nt)
                acc[0][nt] = __builtin_amdgcn_mfma_f32_16x16x32_bf16(a0, whh[ks][nt], acc[0][nt], 0, 0, 0);
            #pragma unroll
            for (int nt = 0; nt < NT; ++nt)
                acc[1][nt] = __builtin_amdgcn_mfma_f32_16x16x32_bf16(a1, whh[ks][nt], acc[1][nt], 0, 0, 0);
        }
        // streamed hh ksteps, SDEPTH-deep pipeline
        #pragma unroll
        for (int ks = RKS; ks < KSH; ++ks) {
            const int s = (ks - RKS) % SDEPTH;
            const bf16x8 a0 = *(const bf16x8*)&hb_r[hb0 + ((ks ^ kx) << 5)];
            const bf16x8 a1 = *(const bf16x8*)&hb_r[hb0 + (16 << 9) + ((ks ^ kx) << 5)];
            #pragma unroll
            for (int nt = 0; nt < NT; ++nt)
                acc[0][nt] = __builtin_amdgcn_mfma_f32_16x16x32_bf16(a0, sB[s][nt], acc[0][nt], 0, 0, 0);
            #pragma unroll
            for (int nt = 0; nt < NT; ++nt)
                acc[1][nt] = __builtin_amdgcn_mfma_f32_16x16x32_bf16(a1, sB[s][nt], acc[1][nt], 0, 0, 0);
            if (ks + SDEPTH < KSH) {
                #pragma unroll
                for (int nt = 0; nt < NT; ++nt)
                    sB[s][nt] = *(const bf16x8*)(Wt + woff[nt] + ((ks + SDEPTH) << 5));
            }
        }
        // write h': C/D layout col=ln, row = mt*16 + 4q + i
        #pragma unroll
        for (int mt = 0; mt < 2; ++mt)
            #pragma unroll
            for (int nt = 0; nt < NT; ++nt) {
                const int cc = (wave << 4) + (nt << 1) + (ln >> 3);  // col>>3
                #pragma unroll
                for (int i = 0; i < 4; ++i) {
                    const int row = (mt << 4) + (q << 2) + i;
                    hb_w[(row << 9) + (((cc ^ (row & 7)) << 3) | (ln & 7))] =
                        (__bf16)fast_tanh(acc[mt][nt][i]);
                }
            }
    };

    stage(0, xbuf[0]);
    __syncthreads();

    #pragma unroll 1
    for (int t = 0; t < T_LEN; t += 2) {
        stage(t + 1, xbuf[1]);                        // t+1 <= 79
        step(hbuf[0], xbuf[0], hbuf[1]);
        __syncthreads();
        if (t + 2 < T_LEN) stage(t + 2, xbuf[0]);
        step(hbuf[1], xbuf[1], hbuf[0]);
        __syncthreads();
    }
    // h_last in hbuf[0], rows 0..31

    // output head: wave reduces 8 rows
    #pragma unroll
    for (int rr = 0; rr < 8; ++rr) {
        const int m = (wave << 3) + rr;
        const bf16x8 hv = *(const bf16x8*)&hbuf[0][(m << 9) + ((lane ^ (m & 7)) << 3)];
        float s = 0.0f;
        #pragma unroll
        for (int j = 0; j < 8; ++j)
            s += (float)hv[j] * Wout[(lane << 3) + j];
        #pragma unroll
        for (int off = 32; off > 0; off >>= 1)
            s += __shfl_down(s, off, 64);
        if (lane == 0) {
            const float logit = s + bout[0];
            out[r0 + m] = __builtin_amdgcn_rcpf(
                1.0f + __builtin_amdgcn_exp2f(-logit * 1.4426950408889634f));
        }
    }
}

extern "C" void kernel_launch(void* const* d_in, const int* in_sizes, int n_in,
                              void* d_out, int out_size, void* d_ws, size_t ws_size,
                              hipStream_t stream) {
    __bf16* Wt = (__bf16*)d_ws;                 // 512*512*2 = 512 KB
    __bf16* Xt = Wt + UNITS * UNITS;            // 512*128*2 = 128 KB
    prep_kernel<<<dim3(320), dim3(256), 0, stream>>>(
        (const float*)d_in[3],   // W_hh
        (const float*)d_in[2],   // W_xh
        Wt, Xt);
    rnn_kernel<<<dim3(NBLK), dim3(NTHR), 0, stream>>>(
        (const int*)d_in[0],     // inputs
        (const float*)d_in[1],   // emb_table
        (const float*)d_in[4],   // b_h
        (const float*)d_in[5],   // W_out
        (const float*)d_in[6],   // b_out
        Wt, Xt,
        (float*)d_out);
}

// Round 4
// 1288.487 us; speedup vs baseline: 1.4262x; 1.4262x over previous
//
#include <hip/hip_runtime.h>
#include <hip/hip_bf16.h>

// MyRnn: h_t = tanh(emb[idx_t] @ W_xh + b_h + h_{t-1} @ W_hh), 80 steps,
// out = sigmoid(h_80 @ W_out + b_out).
//
// R4: spill-proof register budget. Lesson from R1-R3: gfx950 arch VGPRs cap
// at 256 (v0..v255); compiler spills rather than placing loaded weight frags
// in AGPRs. So: design arch demand ~215. 128 blocks x 512 thr (8 waves,
// 2 waves/SIMD, 256-reg total budget via amdgpu_waves_per_eu(2,2)). M=16
// rows/block, NT=4 cols/wave. Resident: W_xh (4 ksteps, 64 regs) + W_hh
// ksteps 0..2 (48 regs). W_hh ksteps 3..15 streamed from L2 (Wt L2-resident,
// 512KB/XCD) with a 2-deep pipeline; ~416 KB/CU/step * 16 CU/XCD / 4.3 TB/s
// = 1.55 us/step ~ the binding pipe (MFMA 1.29 us/step). h double-buffers
// through XOR-swizzled LDS; ONE __syncthreads per step.

#define T_LEN   80
#define EMB_D   100
#define UNITS   512
#define ROWS    16
#define NBLK    128              // 2048/16
#define NTHR    512
#define NT      4                // 16-col n-tiles per wave (64 cols)
#define KSH     16               // hh K-steps (512/32)
#define KSX     4                // x K-steps (128/32, zero-padded)
#define RKS     3                // resident hh ksteps (spill-proof budget)
#define SDEPTH  2                // streamed pipeline depth

typedef __bf16 bf16x8 __attribute__((ext_vector_type(8)));
typedef float  f32x4  __attribute__((ext_vector_type(4)));

__device__ __forceinline__ float fast_tanh(float x) {
    float e = __builtin_amdgcn_exp2f(x * 2.8853900817779268f);
    return 1.0f - 2.0f * __builtin_amdgcn_rcpf(1.0f + e);
}

// ---- prep: transpose + bf16-cast weights into d_ws ----
__global__ void prep_kernel(const float* __restrict__ Whh,
                            const float* __restrict__ Wxh,
                            __bf16* __restrict__ Wt, __bf16* __restrict__ Xt) {
    __shared__ float tile[32][33];
    const int tx = threadIdx.x & 31, ty = threadIdx.x >> 5;  // 32x8
    const int b = blockIdx.x;
    if (b < 256) {
        const int k0 = (b & 15) * 32, n0 = (b >> 4) * 32;
        #pragma unroll
        for (int i = 0; i < 4; ++i)
            tile[ty + 8 * i][tx] = Whh[(k0 + ty + 8 * i) * UNITS + n0 + tx];
        __syncthreads();
        #pragma unroll
        for (int i = 0; i < 4; ++i) {
            const int n = ty + 8 * i;
            Wt[(n0 + n) * UNITS + k0 + tx] = (__bf16)tile[tx][n];
        }
    } else {
        const int bb = b - 256;
        const int k0 = (bb & 3) * 32, n0 = (bb >> 2) * 32;
        #pragma unroll
        for (int i = 0; i < 4; ++i) {
            const int k = k0 + ty + 8 * i;
            tile[ty + 8 * i][tx] = (k < EMB_D) ? Wxh[k * UNITS + n0 + tx] : 0.0f;
        }
        __syncthreads();
        #pragma unroll
        for (int i = 0; i < 4; ++i) {
            const int n = ty + 8 * i;
            Xt[(n0 + n) * 128 + k0 + tx] = (__bf16)tile[tx][n];
        }
    }
}

__global__ __launch_bounds__(NTHR)
__attribute__((amdgpu_waves_per_eu(2, 2)))
void rnn_kernel(const int*   __restrict__ inputs,   // [2048][80]
                const float* __restrict__ emb,      // [35000][100]
                const float* __restrict__ bh,       // [512]
                const float* __restrict__ Wout,     // [512]
                const float* __restrict__ bout,     // [1]
                const __bf16* __restrict__ Wt,      // [512 n][512 k] (ws)
                const __bf16* __restrict__ Xt,      // [512 n][128 k] (ws)
                float*       __restrict__ out)      // [2048]
{
    // h: 16 rows x 512 bf16; elem(r,k) = r*512 + (((k>>3)^(r&7))<<3) + (k&7)
    // x: 16 rows x 128 bf16; same swizzle, row stride 128.
    __shared__ alignas(16) __bf16 hbuf[2][ROWS * UNITS];  // 2 x 16 KB
    __shared__ alignas(16) __bf16 xbuf[2][ROWS * 128];    // 2 x 4 KB

    const int tid  = threadIdx.x;
    const int wave = tid >> 6;       // 0..7
    const int lane = tid & 63;
    const int q    = lane >> 4;
    const int ln   = lane & 15;
    const int e7   = ln & 7;
    const int qa   = q ^ (e7 & 3);
    const int kx   = e7 >> 2;
    const int q8   = q << 3;
    const int r0   = blockIdx.x * ROWS;

    // per-nt element offsets into Wt: frag(ks,nt) = Wt + woff[nt] + ks*32
    int   woff[NT];
    float bhv[NT];
    #pragma unroll
    for (int nt = 0; nt < NT; ++nt) {
        const int col = (wave << 6) + (nt << 4) + ln;
        woff[nt] = col * UNITS + q8;
        bhv[nt]  = bh[col];
    }

    // resident fragments: W_xh (all 4 ksteps) + W_hh ksteps 0..RKS-1
    bf16x8 whh[RKS][NT];
    bf16x8 wxh[KSX][NT];
    #pragma unroll
    for (int nt = 0; nt < NT; ++nt) {
        const int xo = ((wave << 6) + (nt << 4) + ln) * 128 + q8;
        #pragma unroll
        for (int ks = 0; ks < RKS; ++ks)
            whh[ks][nt] = *(const bf16x8*)(Wt + woff[nt] + (ks << 5));
        #pragma unroll
        for (int ks = 0; ks < KSX; ++ks)
            wxh[ks][nt] = *(const bf16x8*)(Xt + xo + (ks << 5));
    }

    // zero LDS: both hbufs (h0 = 0) and both xbufs (pad cols stay 0)
    {
        int4 z; z.x = z.y = z.z = z.w = 0;
        int4* hp = (int4*)&hbuf[0][0];
        #pragma unroll
        for (int i = 0; i < 4; ++i) hp[tid + i * NTHR] = z;   // 32 KB
        int4* xp = (int4*)&xbuf[0][0];
        xp[tid] = z;                                          // 8 KB
    }
    __syncthreads();

    // stage embedded x_t (bf16, swizzled); wave w does rows w and w+8
    auto stage = [&](int t, __bf16* xb) {
        #pragma unroll
        for (int rr = 0; rr < 2; ++rr) {
            const int r = wave + (rr << 3);
            const int idxv = inputs[(r0 + r) * T_LEN + t];
            const float* er = emb + (size_t)idxv * EMB_D;
            const int k0 = lane;          // < 100 always
            xb[(r << 7) + ((((k0 >> 3) ^ (r & 7)) << 3) | (k0 & 7))] = (__bf16)er[k0];
            const int k1 = lane + 64;
            if (k1 < EMB_D)
                xb[(r << 7) + ((((k1 >> 3) ^ (r & 7)) << 3) | (k1 & 7))] = (__bf16)er[k1];
        }
    };

    auto step = [&](const __bf16* hb_r, const __bf16* xb_r, __bf16* hb_w) {
        // prefetch first SDEPTH streamed ksteps (independent of h)
        bf16x8 sB[SDEPTH][NT];
        #pragma unroll
        for (int p = 0; p < SDEPTH; ++p)
            #pragma unroll
            for (int nt = 0; nt < NT; ++nt)
                sB[p][nt] = *(const bf16x8*)(Wt + woff[nt] + ((RKS + p) << 5));

        f32x4 acc[NT];
        #pragma unroll
        for (int nt = 0; nt < NT; ++nt) {
            f32x4 a = {bhv[nt], bhv[nt], bhv[nt], bhv[nt]};
            acc[nt] = a;
        }

        // x contribution (resident) — head start for streamed loads
        const int xb0 = (ln << 7) + (qa << 3);
        #pragma unroll
        for (int ks = 0; ks < KSX; ++ks) {
            const bf16x8 a = *(const bf16x8*)&xb_r[xb0 + ((ks ^ kx) << 5)];
            #pragma unroll
            for (int nt = 0; nt < NT; ++nt)
                acc[nt] = __builtin_amdgcn_mfma_f32_16x16x32_bf16(a, wxh[ks][nt], acc[nt], 0, 0, 0);
        }
        // resident hh ksteps
        const int hb0 = (ln << 9) + (qa << 3);
        #pragma unroll
        for (int ks = 0; ks < RKS; ++ks) {
            const bf16x8 a = *(const bf16x8*)&hb_r[hb0 + ((ks ^ kx) << 5)];
            #pragma unroll
            for (int nt = 0; nt < NT; ++nt)
                acc[nt] = __builtin_amdgcn_mfma_f32_16x16x32_bf16(a, whh[ks][nt], acc[nt], 0, 0, 0);
        }
        // streamed hh ksteps, SDEPTH-deep pipeline
        #pragma unroll
        for (int ks = RKS; ks < KSH; ++ks) {
            const int s = (ks - RKS) % SDEPTH;
            const bf16x8 a = *(const bf16x8*)&hb_r[hb0 + ((ks ^ kx) << 5)];
            #pragma unroll
            for (int nt = 0; nt < NT; ++nt)
                acc[nt] = __builtin_amdgcn_mfma_f32_16x16x32_bf16(a, sB[s][nt], acc[nt], 0, 0, 0);
            if (ks + SDEPTH < KSH) {
                #pragma unroll
                for (int nt = 0; nt < NT; ++nt)
                    sB[s][nt] = *(const bf16x8*)(Wt + woff[nt] + ((ks + SDEPTH) << 5));
            }
        }
        // write h': C/D layout col=ln, row=4q+i
        #pragma unroll
        for (int nt = 0; nt < NT; ++nt) {
            const int cc = (wave << 3) + (nt << 1) + (ln >> 3);  // col>>3
            #pragma unroll
            for (int i = 0; i < 4; ++i) {
                const int row = (q << 2) + i;
                hb_w[(row << 9) + (((cc ^ (row & 7)) << 3) | (ln & 7))] =
                    (__bf16)fast_tanh(acc[nt][i]);
            }
        }
    };

    stage(0, xbuf[0]);
    __syncthreads();

    #pragma unroll 1
    for (int t = 0; t < T_LEN; t += 2) {
        stage(t + 1, xbuf[1]);                        // t+1 <= 79
        step(hbuf[0], xbuf[0], hbuf[1]);
        __syncthreads();
        if (t + 2 < T_LEN) stage(t + 2, xbuf[0]);
        step(hbuf[1], xbuf[1], hbuf[0]);
        __syncthreads();
    }
    // h_last in hbuf[0], rows 0..15

    // output head: wave w reduces rows w and w+8
    #pragma unroll
    for (int rr = 0; rr < 2; ++rr) {
        const int m = wave + (rr << 3);
        const bf16x8 hv = *(const bf16x8*)&hbuf[0][(m << 9) + ((lane ^ wave) << 3)];
        float s = 0.0f;
        #pragma unroll
        for (int j = 0; j < 8; ++j)
            s += (float)hv[j] * Wout[(lane << 3) + j];
        #pragma unroll
        for (int off = 32; off > 0; off >>= 1)
            s += __shfl_down(s, off, 64);
        if (lane == 0) {
            const float logit = s + bout[0];
            out[r0 + m] = __builtin_amdgcn_rcpf(
                1.0f + __builtin_amdgcn_exp2f(-logit * 1.4426950408889634f));
        }
    }
}

extern "C" void kernel_launch(void* const* d_in, const int* in_sizes, int n_in,
                              void* d_out, int out_size, void* d_ws, size_t ws_size,
                              hipStream_t stream) {
    __bf16* Wt = (__bf16*)d_ws;                 // 512*512*2 = 512 KB
    __bf16* Xt = Wt + UNITS * UNITS;            // 512*128*2 = 128 KB
    prep_kernel<<<dim3(320), dim3(256), 0, stream>>>(
        (const float*)d_in[3],   // W_hh
        (const float*)d_in[2],   // W_xh
        Wt, Xt);
    rnn_kernel<<<dim3(NBLK), dim3(NTHR), 0, stream>>>(
        (const int*)d_in[0],     // inputs
        (const float*)d_in[1],   // emb_table
        (const float*)d_in[4],   // b_h
        (const float*)d_in[5],   // W_out
        (const float*)d_in[6],   // b_out
        Wt, Xt,
        (float*)d_out);
}